// Round 12
// baseline (171.035 us; speedup 1.0000x reference)
//
#include <hip/hip_runtime.h>
#include <math.h>

#define Hh 128
#define Ww 128
#define HW (Hh*Ww)
#define Bn 4
#define Cn 64
#define On 64
#define KP 200                // LDS A-row stride (shorts): 192 data + 8 pad
#define OMP 34                // padded px stride for sOM (f16), 32 px
#define NBLK 2048             // dcn grid

typedef __attribute__((ext_vector_type(8))) short bf16x8;
typedef __attribute__((ext_vector_type(4))) float f32x4;
typedef __attribute__((ext_vector_type(4))) unsigned short u16x4;
typedef __attribute__((ext_vector_type(4))) short s16x4;

// fp32 -> bf16 round-to-nearest-even
static __device__ __forceinline__ unsigned short f2bf(float f) {
    unsigned u = __builtin_bit_cast(unsigned, f);
    u += 0x7FFFu + ((u >> 16) & 1u);
    return (unsigned short)(u >> 16);
}
static __device__ __forceinline__ float bf2f(unsigned short s) {
    unsigned u = ((unsigned)s) << 16;
    return __builtin_bit_cast(float, u);
}
static __device__ __forceinline__ short f2h(float f) {
    _Float16 h = (_Float16)f;
    return __builtin_bit_cast(short, h);
}
static __device__ __forceinline__ float h2f(short s) {
    return (float)__builtin_bit_cast(_Float16, s);
}

// workspace layout (bytes): xtb(8M) | conv(16M) | part(1M) | ss | owT | dwT
#define XTB_BYTES   ((size_t)Bn*HW*64*2)
#define CONV_BYTES  ((size_t)Bn*On*HW*4)
#define PART_BYTES  ((size_t)128*NBLK*4)

// ---------------------------------------------------------------------------
// Prep: blocks 0..511 = NCHW->NHWC bf16 transpose (one (b,h) row each);
//       blocks 512..727 = weight pack bf16 tap-major [o][tap][c].
// ---------------------------------------------------------------------------
__global__ __launch_bounds__(256) void prep_k(
    const float* __restrict__ x,  const float* __restrict__ ow,
    const float* __restrict__ dw, unsigned short* __restrict__ xtb,
    short* __restrict__ owT,      short* __restrict__ dwT)
{
    int blk = blockIdx.x;
    int t = threadIdx.x;
    if (blk < 512) {
        int b = blk >> 7, h = blk & 127;
        __shared__ float sT[64 * 133];
        const float* xp = x + (size_t)b * Cn * HW + (size_t)h * Ww;
#pragma unroll
        for (int it = 0; it < 32; ++it) {
            int idx = t + 256 * it;        // c(6b) | w(7b)
            int c = idx >> 7, w = idx & 127;
            sT[c * 133 + w] = xp[(size_t)c * HW + w];
        }
        __syncthreads();
        unsigned short* op = xtb + (size_t)blk * Ww * 64;
#pragma unroll
        for (int it = 0; it < 32; ++it) {
            int idx = t + 256 * it;        // w(7b) | c(6b)
            int w = idx >> 6, c = idx & 63;
            op[(size_t)w * 64 + c] = f2bf(sT[c * 133 + w]);
        }
    } else {
        int u = (blk - 512) * 4 + (t >> 6);   // 0..863
        int c = t & 63;
        if (u < 288) {
            int o = u / 9, kk = u % 9;
            float v = (o < 27) ? ow[(size_t)o * 576 + c * 9 + kk] : 0.0f;
            owT[(size_t)u * 64 + c] = (short)f2bf(v);
        } else {
            int u2 = u - 288;
            int o = u2 / 9, kk = u2 % 9;
            dwT[(size_t)u2 * 64 + c] = (short)f2bf(dw[(size_t)o * 576 + c * 9 + kk]);
        }
    }
}

// ---------------------------------------------------------------------------
// Fused: offset-conv GEMM -> per-thread bilinear prep -> coalesced sampling
// fill -> DCN GEMM -> conv store + BN stats partials (transposed part).
// Block = QUARTER-row (32 px), grid 2048, XCD-swizzled -> 8 blocks/CU,
// 32 waves/CU (R10 at 4 blocks/CU was latency-bound: all pipes <35%).
// x is bf16 NHWC: phase-1 fill is a raw copy; corner gathers 128 B/unit.
// CRITICAL #1: no __launch_bounds__ min-waves arg (R3 spill disaster).
// CRITICAL #2: wave id readfirstlane'd (R4 divergent-uniform trap).
// MFMA 16x16x32 bf16: A lane=[m=l15][k=quad*8+j]; B lane=[k=quad*8+j][n=l15];
// D lane=[row=quad*4+r][col=l15]  (validated R8-R10).
// LDS: sA 12800 + sOMh ~1860 + prepIdx 2304 + prepW 2304 ~= 19.3 KB.
// ---------------------------------------------------------------------------
__global__ __launch_bounds__(256) void dcn_fused_k(
    const unsigned short* __restrict__ xtb, const short* __restrict__ owT,
    const float* __restrict__ ob,           const short* __restrict__ dwT,
    float* __restrict__ conv,               float* __restrict__ part)
{
    // XCD swizzle: blk = xcd*256 + slab -> each XCD owns a contiguous
    // (b, h-slab) ~1 MB bf16 working set, fits its 4 MB L2.
    int raw  = blockIdx.x;
    int blk  = ((raw & 7) << 8) | (raw >> 3);   // b(2b) | h(7b) | q(2b)
    int q    = blk & 3;
    int h    = (blk >> 2) & 127;
    int b    = blk >> 9;
    int px0  = q * 32;
    int t    = threadIdx.x;
    int lane = t & 63;
    int quad = lane >> 4;
    int l15  = lane & 15;
    int w_s  = __builtin_amdgcn_readfirstlane(t >> 6);   // 0..3 (SGPR)

    __shared__ __align__(16) short sA[32 * KP];               // 12800 B
    __shared__ __align__(16) short sOMh[27 * OMP + 12];       //  1860 B
    __shared__ __align__(16) unsigned short prepIdx[288 * 4]; //  2304 B
    __shared__ __align__(16) short prepW[288 * 4];            //  2304 B

    const unsigned short* xbh = xtb + (size_t)b * HW * 64;

    // ================= Phase 1: offset conv GEMM (M=32, N=32) ============
    int nt_o = w_s & 1;
    int mh   = w_s >> 1;
    int o_ow = nt_o * 16 + l15;
    f32x4 oacc = {0, 0, 0, 0};

    for (int ck = 0; ck < 3; ++ck) {
        // ---- im2col fill: 96 units (kkl x px), wave-uniform, lanes = c
#pragma unroll 4
        for (int uu = 0; uu < 24; ++uu) {
            int unit = uu * 4 + w_s;
            int kkl = unit >> 5, px = unit & 31;
            int yy = h + ck - 1;
            int xx = px0 + px + kkl - 1;
            bool valid = ((unsigned)yy < (unsigned)Hh) && ((unsigned)xx < (unsigned)Ww);
            unsigned short v = valid ? xbh[(((size_t)yy * Ww + xx) << 6) + lane] : 0;
            sA[px * KP + kkl * 64 + lane] = (short)v;
        }
        __syncthreads();
#pragma unroll
        for (int ks = 0; ks < 6; ++ks) {
            int kk = ck * 3 + (ks >> 1);
            bf16x8 bfr = *(const bf16x8*)&owT[((size_t)o_ow * 9 + kk) * 64
                                             + (ks & 1) * 32 + quad * 8];
            bf16x8 a = *(const bf16x8*)&sA[(mh * 16 + l15) * KP
                                           + ks * 32 + quad * 8];
            oacc = __builtin_amdgcn_mfma_f32_16x16x32_bf16(a, bfr, oacc, 0, 0, 0);
        }
        __syncthreads();
    }
    // ---- D -> sOMh (+bias), f16; px = mh*16 + quad*4 + r
    if (o_ow < 27) {
        float bias = ob[o_ow];
        int pxb = mh * 16 + quad * 4;
#pragma unroll
        for (int r = 0; r < 4; ++r)
            sOMh[o_ow * OMP + pxb + r] = f2h(oacc[r] + bias);
    }
    __syncthreads();

    // ================= Phase 2: per-thread bilinear prep -> LDS ==========
    // 288 units = tap(9) x px(32); thread owns u = t (+256 for t<32)
#pragma unroll
    for (int i = 0; i < 2; ++i) {
        int u = t + 256 * i;
        if (u < 288) {
            int kk = u >> 5, px = u & 31;
            float ox = h2f(sOMh[kk * OMP + px]);
            float oy = h2f(sOMh[(9 + kk) * OMP + px]);
            float mr = h2f(sOMh[(18 + kk) * OMP + px]);
            float m  = 1.0f / (1.0f + __expf(-mr));
            float py  = (float)(h - 1 + (kk / 3)) + oy;
            float pxf = (float)(px0 + px - 1 + (kk % 3)) + ox;
            float y0f = floorf(py), x0f = floorf(pxf);
            int y0 = (int)y0f, x0 = (int)x0f;
            float wy = py - y0f, wx = pxf - x0f;
#pragma unroll
            for (int dy = 0; dy < 2; ++dy) {
#pragma unroll
                for (int dx = 0; dx < 2; ++dx) {
                    int yi = y0 + dy, xi = x0 + dx;
                    bool valid = (yi >= 0) && (yi < Hh) && (xi >= 0) && (xi < Ww);
                    int yc = min(max(yi, 0), Hh - 1);
                    int xc = min(max(xi, 0), Ww - 1);
                    float wgt = (dy ? wy : 1.0f - wy) * (dx ? wx : 1.0f - wx);
                    prepIdx[u * 4 + dy * 2 + dx] = (unsigned short)(yc * Ww + xc);
                    prepW[u * 4 + dy * 2 + dx]   = f2h(valid ? (wgt * m) : 0.0f);
                }
            }
        }
    }
    __syncthreads();

    // ================= Phase 3: sampling fill + DCN GEMM (M=32, N=64) ====
    int o_dw = w_s * 16 + l15;
    f32x4 acc[2] = {{0,0,0,0},{0,0,0,0}};

    for (int ck = 0; ck < 3; ++ck) {
#pragma unroll 4
        for (int uu = 0; uu < 24; ++uu) {
            int unit = uu * 4 + w_s;             // wave-uniform
            int kkl = unit >> 5, px = unit & 31;
            int u = (ck * 3 + kkl) * 32 + px;
            u16x4 pi = *(const u16x4*)&prepIdx[u * 4];   // broadcast ds_read
            s16x4  pw = *(const s16x4*)&prepW[u * 4];
            float v = 0.0f;
#pragma unroll
            for (int j = 0; j < 4; ++j) {
                float cv = bf2f(xbh[((size_t)pi[j] << 6) + lane]);  // 128 B coalesced
                v += h2f(pw[j]) * cv;
            }
            sA[px * KP + kkl * 64 + lane] = (short)f2bf(v);
        }
        __syncthreads();
#pragma unroll
        for (int ks = 0; ks < 6; ++ks) {
            int kk = ck * 3 + (ks >> 1);
            bf16x8 bfr = *(const bf16x8*)&dwT[((size_t)o_dw * 9 + kk) * 64
                                              + (ks & 1) * 32 + quad * 8];
#pragma unroll
            for (int mt = 0; mt < 2; ++mt) {
                bf16x8 a = *(const bf16x8*)&sA[(mt * 16 + l15) * KP
                                               + ks * 32 + quad * 8];
                acc[mt] = __builtin_amdgcn_mfma_f32_16x16x32_bf16(a, bfr, acc[mt], 0, 0, 0);
            }
        }
        __syncthreads();
    }

    // ================= Phase 4: store conv + stats partials =================
#pragma unroll
    for (int mt = 0; mt < 2; ++mt) {
        size_t idx = ((size_t)b * On + o_dw) * HW + (size_t)h * Ww + px0 + mt * 16 + quad * 4;
        *(f32x4*)(conv + idx) = acc[mt];
    }
    float s1 = 0.0f, s2 = 0.0f;
#pragma unroll
    for (int mt = 0; mt < 2; ++mt) {
#pragma unroll
        for (int r = 0; r < 4; ++r) {
            float v = acc[mt][r];
            s1 += v;
            s2 += v * v;
        }
    }
    s1 += __shfl_down(s1, 32, 64);  s2 += __shfl_down(s2, 32, 64);
    s1 += __shfl_down(s1, 16, 64);  s2 += __shfl_down(s2, 16, 64);
    if (lane < 16) {
        part[(size_t)o_dw * NBLK + blk]        = s1;
        part[(size_t)(64 + o_dw) * NBLK + blk] = s2;
    }
}

// ---------------------------------------------------------------------------
// Stats reduce: part is [chan128][NBLK]. Block o sums channel o (sum) and
// 64+o (sumsq) over NBLK coalesced -> ss[o], ss[64+o].  64 blocks ~ 3 us.
// ---------------------------------------------------------------------------
__global__ __launch_bounds__(256) void stats_k(
    const float* __restrict__ part, const float* __restrict__ gamma,
    const float* __restrict__ beta, float* __restrict__ ss)
{
    int o = blockIdx.x;
    int t = threadIdx.x;
    float s1 = 0.0f, s2 = 0.0f;
    for (int i = t; i < NBLK; i += 256) {
        s1 += part[(size_t)o * NBLK + i];
        s2 += part[(size_t)(64 + o) * NBLK + i];
    }
#pragma unroll
    for (int off = 32; off > 0; off >>= 1) {
        s1 += __shfl_down(s1, off, 64);
        s2 += __shfl_down(s2, off, 64);
    }
    __shared__ float r1[4], r2[4];
    if ((t & 63) == 0) { r1[t >> 6] = s1; r2[t >> 6] = s2; }
    __syncthreads();
    if (t == 0) {
        float S1 = r1[0] + r1[1] + r1[2] + r1[3];
        float S2 = r2[0] + r2[1] + r2[2] + r2[3];
        float n = (float)(Bn * HW);
        float mu = S1 / n;
        float var = S2 / n - mu * mu;
        float sc = gamma[o] * rsqrtf(var + 1e-5f);
        ss[o] = sc;
        ss[64 + o] = beta[o] - mu * sc;
    }
}

// ---------------------------------------------------------------------------
// BN + ReLU apply, float4
// ---------------------------------------------------------------------------
__global__ __launch_bounds__(256) void bnrelu_k(
    const float* __restrict__ conv, const float* __restrict__ ss,
    float* __restrict__ out)
{
    int i = blockIdx.x * blockDim.x + threadIdx.x;
    int ch = (i >> 12) & 63;
    float sc = ss[ch];
    float sh = ss[64 + ch];
    const float4* cv = (const float4*)conv;
    float4* ov = (float4*)out;
    float4 v = cv[i];
    v.x = fmaxf(v.x * sc + sh, 0.0f);
    v.y = fmaxf(v.y * sc + sh, 0.0f);
    v.z = fmaxf(v.z * sc + sh, 0.0f);
    v.w = fmaxf(v.w * sc + sh, 0.0f);
    ov[i] = v;
}

// ---------------------------------------------------------------------------
extern "C" void kernel_launch(void* const* d_in, const int* in_sizes, int n_in,
                              void* d_out, int out_size, void* d_ws, size_t ws_size,
                              hipStream_t stream)
{
    const float* x     = (const float*)d_in[0];
    const float* ow    = (const float*)d_in[1];
    const float* ob    = (const float*)d_in[2];
    const float* dw    = (const float*)d_in[3];
    // d_in[4] = dcn_b: cancels exactly under BN mean subtraction -> unused
    const float* gamma = (const float*)d_in[5];
    const float* beta  = (const float*)d_in[6];

    char* wsb = (char*)d_ws;
    unsigned short* xtb = (unsigned short*)wsb;
    float* conv = (float*)(wsb + XTB_BYTES);
    float* part = (float*)(wsb + XTB_BYTES + CONV_BYTES);
    float* ss   = (float*)(wsb + XTB_BYTES + CONV_BYTES + PART_BYTES);
    short* owT  = (short*)(wsb + XTB_BYTES + CONV_BYTES + PART_BYTES + 512);
    short* dwT  = owT + 288 * 64;

    prep_k     <<<dim3(728),  dim3(256), 0, stream>>>(x, ow, dw, xtb, owT, dwT);
    dcn_fused_k<<<dim3(NBLK), dim3(256), 0, stream>>>(xtb, owT, ob, dwT, conv, part);
    stats_k    <<<dim3(64),   dim3(256), 0, stream>>>(part, gamma, beta, ss);
    bnrelu_k   <<<dim3(Bn * On * HW / 4 / 256), dim3(256), 0, stream>>>(conv, ss, (float*)d_out);
}

// Round 15
// 151.370 us; speedup vs baseline: 1.1299x; 1.1299x over previous
//
#include <hip/hip_runtime.h>
#include <math.h>

#define Hh 128
#define Ww 128
#define HW (Hh*Ww)
#define Bn 4
#define Cn 64
#define On 64
#define KP 200                // LDS A-row stride (shorts): 192 data + 8 pad
#define OMP 66                // padded px stride for sOM (f16), 64 px
#define NBLK 1024             // dcn grid (half-row blocks)

typedef __attribute__((ext_vector_type(8))) short bf16x8;
typedef __attribute__((ext_vector_type(4))) float f32x4;
typedef __attribute__((ext_vector_type(4))) unsigned short u16x4;
typedef __attribute__((ext_vector_type(4))) short s16x4;

// fp32 -> bf16 round-to-nearest-even
static __device__ __forceinline__ unsigned short f2bf(float f) {
    unsigned u = __builtin_bit_cast(unsigned, f);
    u += 0x7FFFu + ((u >> 16) & 1u);
    return (unsigned short)(u >> 16);
}
static __device__ __forceinline__ float bf2f(unsigned short s) {
    unsigned u = ((unsigned)s) << 16;
    return __builtin_bit_cast(float, u);
}
static __device__ __forceinline__ short f2h(float f) {
    _Float16 h = (_Float16)f;
    return __builtin_bit_cast(short, h);
}
static __device__ __forceinline__ float h2f(short s) {
    return (float)__builtin_bit_cast(_Float16, s);
}

// workspace layout (bytes): xtb(8M) | conv(16M) | part(512K) | ss | owT | dwT
#define XTB_BYTES   ((size_t)Bn*HW*64*2)
#define CONV_BYTES  ((size_t)Bn*On*HW*4)
#define PART_BYTES  ((size_t)128*NBLK*4)

// ---------------------------------------------------------------------------
// Prep: blocks 0..511 = NCHW->NHWC bf16 transpose (one (b,h) row each);
//       blocks 512..727 = weight pack bf16 tap-major [o][tap][c].
// ---------------------------------------------------------------------------
__global__ __launch_bounds__(256) void prep_k(
    const float* __restrict__ x,  const float* __restrict__ ow,
    const float* __restrict__ dw, unsigned* __restrict__ xtb,
    short* __restrict__ owT,      short* __restrict__ dwT)
{
    int blk = blockIdx.x;
    int t = threadIdx.x;
    if (blk < 512) {
        int b = blk >> 7, h = blk & 127;
        __shared__ float sT[64 * 133];
        const float* xp = x + (size_t)b * Cn * HW + (size_t)h * Ww;
#pragma unroll
        for (int it = 0; it < 32; ++it) {
            int idx = t + 256 * it;        // c(6b) | w(7b)
            int c = idx >> 7, w = idx & 127;
            sT[c * 133 + w] = xp[(size_t)c * HW + w];
        }
        __syncthreads();
        unsigned* op = xtb + (size_t)blk * Ww * 32;   // 32 dwords (64 bf16)/px
#pragma unroll
        for (int it = 0; it < 16; ++it) {
            int idx = t + 256 * it;        // w(7b) | cp(5b)
            int w = idx >> 5, cp = idx & 31;
            unsigned lo = f2bf(sT[(2 * cp) * 133 + w]);
            unsigned hi = f2bf(sT[(2 * cp + 1) * 133 + w]);
            op[(size_t)w * 32 + cp] = lo | (hi << 16);
        }
    } else {
        int u = (blk - 512) * 4 + (t >> 6);   // 0..863
        int c = t & 63;
        if (u < 288) {
            int o = u / 9, kk = u % 9;
            float v = (o < 27) ? ow[(size_t)o * 576 + c * 9 + kk] : 0.0f;
            owT[(size_t)u * 64 + c] = (short)f2bf(v);
        } else {
            int u2 = u - 288;
            int o = u2 / 9, kk = u2 % 9;
            dwT[(size_t)u2 * 64 + c] = (short)f2bf(dw[(size_t)o * 576 + c * 9 + kk]);
        }
    }
}

// ---------------------------------------------------------------------------
// Fused: offset-conv GEMM -> per-thread bilinear prep -> sampling fill ->
// DCN GEMM -> conv store + BN stats partials (transposed part).
// Block = HALF-row (64 px; quarter-row R12 regressed dcn 76->91 us), grid
// 1024, XCD-swizzled. x is bf16 NHWC (dword = 2 channels).
// Phase-1 fill = pure dword copy, 2 px per wave-iter (no math).
// CRITICAL #1: no __launch_bounds__ min-waves arg (R3 spill disaster).
// CRITICAL #2: wave id readfirstlane'd (R4 divergent-uniform trap).
// MFMA 16x16x32 bf16 (validated R8-R12):
//   A lane=[m=l15][k=quad*8+j]; B lane=[k=quad*8+j][n=l15];
//   D lane=[row=quad*4+r][col=l15].
// LDS: sA 25600 + sOMh 3612 + prepIdx 4608 + prepW 4608 ~= 38.4 KB -> 4/CU.
// ---------------------------------------------------------------------------
__global__ __launch_bounds__(256) void dcn_fused_k(
    const unsigned* __restrict__ xtb, const short* __restrict__ owT,
    const float* __restrict__ ob,     const short* __restrict__ dwT,
    float* __restrict__ conv,         float* __restrict__ part)
{
    int raw  = blockIdx.x;
    int blk  = ((raw & 7) << 7) | (raw >> 3);   // b(2b) | h(7b) | half(1b)
    int half = blk & 1;
    int h    = (blk >> 1) & 127;
    int b    = blk >> 8;
    int px0  = half * 64;
    int t    = threadIdx.x;
    int lane = t & 63;
    int quad = lane >> 4;
    int l15  = lane & 15;
    int hl   = lane >> 5;          // px-parity within a pair (phase 1)
    int cl   = lane & 31;          // channel-pair index 0..31 (phase 1)
    int w_s  = __builtin_amdgcn_readfirstlane(t >> 6);   // 0..3 (SGPR)

    __shared__ __align__(16) short sA[64 * KP];               // 25600 B (bf16)
    __shared__ __align__(16) short sOMh[27 * OMP + 12];       //  3612 B (f16)
    __shared__ __align__(16) unsigned short prepIdx[576 * 4]; //  4608 B
    __shared__ __align__(16) short prepW[576 * 4];            //  4608 B (f16)

    const unsigned* xbd = xtb + (size_t)b * HW * 32;               // dword view
    const unsigned short* xbs = (const unsigned short*)xbd;        // ushort view
    unsigned* sAd = (unsigned*)sA;                                 // row = 100 dw

    // ================= Phase 1: offset conv GEMM (M=64, N=32) ============
    int nt_o = w_s & 1;
    int mh   = w_s >> 1;
    int o_ow = nt_o * 16 + l15;
    f32x4 oacc[2] = {{0,0,0,0},{0,0,0,0}};

    for (int ck = 0; ck < 3; ++ck) {
        // ---- im2col fill: 96 px-pairs x 3 kkl; pure dword copy
#pragma unroll 4
        for (int pr = 0; pr < 24; ++pr) {
            int pair = pr * 4 + w_s;
            int kkl = pair >> 5, px2 = pair & 31;
            int px = px2 * 2 + hl;
            int yy = h + ck - 1;
            int xx = px0 + px + kkl - 1;
            bool valid = ((unsigned)yy < (unsigned)Hh) && ((unsigned)xx < (unsigned)Ww);
            unsigned v = valid ? xbd[(((size_t)yy << 7) + xx) * 32 + cl] : 0u;
            sAd[px * 100 + kkl * 32 + cl] = v;
        }
        __syncthreads();
#pragma unroll
        for (int ks = 0; ks < 6; ++ks) {
            int kk = ck * 3 + (ks >> 1);
            bf16x8 bfr = *(const bf16x8*)&owT[((size_t)o_ow * 9 + kk) * 64
                                             + (ks & 1) * 32 + quad * 8];
#pragma unroll
            for (int m2 = 0; m2 < 2; ++m2) {
                bf16x8 a = *(const bf16x8*)&sA[(mh * 32 + m2 * 16 + l15) * KP
                                               + ks * 32 + quad * 8];
                oacc[m2] = __builtin_amdgcn_mfma_f32_16x16x32_bf16(a, bfr, oacc[m2], 0, 0, 0);
            }
        }
        __syncthreads();
    }
    // ---- D -> sOMh (+bias), f16; px = (mh*2+m2)*16 + quad*4 + r
    if (o_ow < 27) {
        float bias = ob[o_ow];
#pragma unroll
        for (int m2 = 0; m2 < 2; ++m2) {
            int pxb = (mh * 2 + m2) * 16 + quad * 4;
#pragma unroll
            for (int r = 0; r < 4; ++r)
                sOMh[o_ow * OMP + pxb + r] = f2h(oacc[m2][r] + bias);
        }
    }
    __syncthreads();

    // ================= Phase 2: per-thread bilinear prep -> LDS ==========
    // 576 units = tap(9) x px(64); thread owns u = t, t+256, t+512(<576)
#pragma unroll
    for (int i = 0; i < 3; ++i) {
        int u = t + 256 * i;
        if (u < 576) {
            int kk = u >> 6, px = u & 63;
            float ox = h2f(sOMh[kk * OMP + px]);
            float oy = h2f(sOMh[(9 + kk) * OMP + px]);
            float mr = h2f(sOMh[(18 + kk) * OMP + px]);
            float m  = 1.0f / (1.0f + __expf(-mr));
            float py  = (float)(h - 1 + (kk / 3)) + oy;
            float pxf = (float)(px0 + px - 1 + (kk % 3)) + ox;
            float y0f = floorf(py), x0f = floorf(pxf);
            int y0 = (int)y0f, x0 = (int)x0f;
            float wy = py - y0f, wx = pxf - x0f;
#pragma unroll
            for (int dy = 0; dy < 2; ++dy) {
#pragma unroll
                for (int dx = 0; dx < 2; ++dx) {
                    int yi = y0 + dy, xi = x0 + dx;
                    bool valid = (yi >= 0) && (yi < Hh) && (xi >= 0) && (xi < Ww);
                    int yc = min(max(yi, 0), Hh - 1);
                    int xc = min(max(xi, 0), Ww - 1);
                    float wgt = (dy ? wy : 1.0f - wy) * (dx ? wx : 1.0f - wx);
                    prepIdx[u * 4 + dy * 2 + dx] = (unsigned short)(yc * Ww + xc);
                    prepW[u * 4 + dy * 2 + dx]   = f2h(valid ? (wgt * m) : 0.0f);
                }
            }
        }
    }
    __syncthreads();

    // ================= Phase 3: sampling fill + DCN GEMM (M=64, N=64) ====
    int o_dw = w_s * 16 + l15;
    f32x4 acc[4] = {{0,0,0,0},{0,0,0,0},{0,0,0,0},{0,0,0,0}};

    for (int ck = 0; ck < 3; ++ck) {
#pragma unroll 4
        for (int uu = 0; uu < 48; ++uu) {
            int unit = uu * 4 + w_s;             // wave-uniform
            int kkl = unit >> 6, px = unit & 63;
            int u = (ck * 3 + kkl) * 64 + px;
            u16x4 pi = *(const u16x4*)&prepIdx[u * 4];   // broadcast ds_read_b64
            s16x4 pw = *(const s16x4*)&prepW[u * 4];
            float v = 0.0f;
#pragma unroll
            for (int j = 0; j < 4; ++j) {
                float cv = bf2f(xbs[(size_t)pi[j] * 64 + lane]);  // 128 B coalesced
                v += h2f(pw[j]) * cv;
            }
            sA[px * KP + kkl * 64 + lane] = (short)f2bf(v);
        }
        __syncthreads();
#pragma unroll
        for (int ks = 0; ks < 6; ++ks) {
            int kk = ck * 3 + (ks >> 1);
            bf16x8 bfr = *(const bf16x8*)&dwT[((size_t)o_dw * 9 + kk) * 64
                                              + (ks & 1) * 32 + quad * 8];
#pragma unroll
            for (int mt = 0; mt < 4; ++mt) {
                bf16x8 a = *(const bf16x8*)&sA[(mt * 16 + l15) * KP
                                               + ks * 32 + quad * 8];
                acc[mt] = __builtin_amdgcn_mfma_f32_16x16x32_bf16(a, bfr, acc[mt], 0, 0, 0);
            }
        }
        __syncthreads();
    }

    // ================= Phase 4: store conv + stats partials =================
#pragma unroll
    for (int mt = 0; mt < 4; ++mt) {
        size_t idx = ((size_t)b * On + o_dw) * HW + (size_t)h * Ww + px0 + mt * 16 + quad * 4;
        *(f32x4*)(conv + idx) = acc[mt];
    }
    float s1 = 0.0f, s2 = 0.0f;
#pragma unroll
    for (int mt = 0; mt < 4; ++mt) {
#pragma unroll
        for (int r = 0; r < 4; ++r) {
            float v = acc[mt][r];
            s1 += v;
            s2 += v * v;
        }
    }
    s1 += __shfl_down(s1, 32, 64);  s2 += __shfl_down(s2, 32, 64);
    s1 += __shfl_down(s1, 16, 64);  s2 += __shfl_down(s2, 16, 64);
    if (lane < 16) {
        part[(size_t)o_dw * NBLK + blk]        = s1;
        part[(size_t)(64 + o_dw) * NBLK + blk] = s2;
    }
}

// ---------------------------------------------------------------------------
// Stats reduce: part is [chan128][NBLK]. Block o sums channel o (sum) and
// 64+o (sumsq) coalesced -> ss[o], ss[64+o].
// ---------------------------------------------------------------------------
__global__ __launch_bounds__(256) void stats_k(
    const float* __restrict__ part, const float* __restrict__ gamma,
    const float* __restrict__ beta, float* __restrict__ ss)
{
    int o = blockIdx.x;
    int t = threadIdx.x;
    float s1 = 0.0f, s2 = 0.0f;
    for (int i = t; i < NBLK; i += 256) {
        s1 += part[(size_t)o * NBLK + i];
        s2 += part[(size_t)(64 + o) * NBLK + i];
    }
#pragma unroll
    for (int off = 32; off > 0; off >>= 1) {
        s1 += __shfl_down(s1, off, 64);
        s2 += __shfl_down(s2, off, 64);
    }
    __shared__ float r1[4], r2[4];
    if ((t & 63) == 0) { r1[t >> 6] = s1; r2[t >> 6] = s2; }
    __syncthreads();
    if (t == 0) {
        float S1 = r1[0] + r1[1] + r1[2] + r1[3];
        float S2 = r2[0] + r2[1] + r2[2] + r2[3];
        float n = (float)(Bn * HW);
        float mu = S1 / n;
        float var = S2 / n - mu * mu;
        float sc = gamma[o] * rsqrtf(var + 1e-5f);
        ss[o] = sc;
        ss[64 + o] = beta[o] - mu * sc;
    }
}

// ---------------------------------------------------------------------------
// BN + ReLU apply, float4
// ---------------------------------------------------------------------------
__global__ __launch_bounds__(256) void bnrelu_k(
    const float* __restrict__ conv, const float* __restrict__ ss,
    float* __restrict__ out)
{
    int i = blockIdx.x * blockDim.x + threadIdx.x;
    int ch = (i >> 12) & 63;
    float sc = ss[ch];
    float sh = ss[64 + ch];
    const float4* cv = (const float4*)conv;
    float4* ov = (float4*)out;
    float4 v = cv[i];
    v.x = fmaxf(v.x * sc + sh, 0.0f);
    v.y = fmaxf(v.y * sc + sh, 0.0f);
    v.z = fmaxf(v.z * sc + sh, 0.0f);
    v.w = fmaxf(v.w * sc + sh, 0.0f);
    ov[i] = v;
}

// ---------------------------------------------------------------------------
extern "C" void kernel_launch(void* const* d_in, const int* in_sizes, int n_in,
                              void* d_out, int out_size, void* d_ws, size_t ws_size,
                              hipStream_t stream)
{
    const float* x     = (const float*)d_in[0];
    const float* ow    = (const float*)d_in[1];
    const float* ob    = (const float*)d_in[2];
    const float* dw    = (const float*)d_in[3];
    // d_in[4] = dcn_b: cancels exactly under BN mean subtraction -> unused
    const float* gamma = (const float*)d_in[5];
    const float* beta  = (const float*)d_in[6];

    char* wsb = (char*)d_ws;
    unsigned* xtb = (unsigned*)wsb;
    float* conv = (float*)(wsb + XTB_BYTES);
    float* part = (float*)(wsb + XTB_BYTES + CONV_BYTES);
    float* ss   = (float*)(wsb + XTB_BYTES + CONV_BYTES + PART_BYTES);
    short* owT  = (short*)(wsb + XTB_BYTES + CONV_BYTES + PART_BYTES + 512);
    short* dwT  = owT + 288 * 64;

    prep_k     <<<dim3(728),  dim3(256), 0, stream>>>(x, ow, dw, xtb, owT, dwT);
    dcn_fused_k<<<dim3(NBLK), dim3(256), 0, stream>>>(xtb, owT, ob, dwT, conv, part);
    stats_k    <<<dim3(64),   dim3(256), 0, stream>>>(part, gamma, beta, ss);
    bnrelu_k   <<<dim3(Bn * On * HW / 4 / 256), dim3(256), 0, stream>>>(conv, ss, (float*)d_out);
}